// Round 1
// baseline (303.750 us; speedup 1.0000x reference)
//
#include <hip/hip_runtime.h>
#include <hip/hip_bf16.h>

// Problem constants
#define BB 2048
#define NN 100
#define INF_ 64
#define HH 256
#define CC 3
// M = B*N
#define MM 204800

static __device__ __forceinline__ float bf2f(unsigned short u) {
    union { float f; unsigned int i; } c;
    c.i = ((unsigned int)u) << 16;
    return c.f;
}

// ---------------------------------------------------------------------------
// Kernel P: precompute Wcomb[z][64][256] = W_exp @ W_{l,r}[2]
//           and cadd[z][100][256] = (b_exp + pe[n]) @ W_{l,r}[2] + b_{l,r}[2]
// grid: (164, 2) x 256 threads. r<64 -> Wcomb row, else cadd row (n = r-64).
// ---------------------------------------------------------------------------
__global__ __launch_bounds__(256) void precompute_k(
    const float* __restrict__ W_exp, const float* __restrict__ b_exp,
    const float* __restrict__ W_l, const float* __restrict__ b_l,
    const float* __restrict__ W_r, const float* __restrict__ b_r,
    float* __restrict__ Wcomb, float* __restrict__ cadd)
{
    int r = blockIdx.x;           // 0..163
    int z = blockIdx.y;           // 0 = l, 1 = r
    int t = threadIdx.x;          // 0..255 (output col)
    const float* Wg = (z ? W_r : W_l) + 2 * HH * HH;  // layer 2, [256,256]
    const float* bg = (z ? b_r : b_l) + 2 * HH;

    __shared__ float sa[HH];
    float a;
    if (r < INF_) {
        a = W_exp[r * HH + t];
    } else {
        int n = r - INF_;
        // pe[n, t]: k2 = t & ~1 ; div = exp(k2 * (-ln(10000)/256))
        float div = expf((float)(t & 254) * (-0.03597789207803f));
        float ang = (float)n * div;
        a = b_exp[t] + ((t & 1) ? cosf(ang) : sinf(ang));
    }
    sa[t] = a;
    __syncthreads();

    float acc = 0.f;
    #pragma unroll 8
    for (int h = 0; h < HH; ++h)
        acc += sa[h] * Wg[h * HH + t];

    if (r < INF_) Wcomb[(z * INF_ + r) * HH + t] = acc;
    else          cadd[(z * NN + (r - INF_)) * HH + t] = acc + bg[t];
}

// ---------------------------------------------------------------------------
// Kernel G: xl/xr[m, n] = x[m, :64] @ Wcomb_z[:64, n] + cadd_z[m % 100, n]
// M=204800, K=64, N=256. Tile 128x128, BK=32, 256 thr, 8x8 microtile.
// Output stored as bf16.
// ---------------------------------------------------------------------------
#define G_BM 128
#define G_BN 128

__global__ __launch_bounds__(256) void gemm_xlr_k(
    const float* __restrict__ x, const float* __restrict__ Wcomb,
    const float* __restrict__ cadd,
    __hip_bfloat16* __restrict__ xl, __hip_bfloat16* __restrict__ xr)
{
    int z = blockIdx.z;
    const float* W  = Wcomb + z * INF_ * HH;
    const float* cb = cadd + z * NN * HH;
    __hip_bfloat16* out = z ? xr : xl;

    int bm = blockIdx.x * G_BM;
    int bn = blockIdx.y * G_BN;
    int t = threadIdx.x;

    __shared__ float As[32][G_BM + 4];   // transposed: As[k][m]
    __shared__ float Bs[32][G_BN + 4];

    float acc[8][8];
    #pragma unroll
    for (int i = 0; i < 8; ++i)
        #pragma unroll
        for (int j = 0; j < 8; ++j) acc[i][j] = 0.f;

    int tr = t >> 4, tc = t & 15;

    for (int ks = 0; ks < INF_; ks += 32) {
        // load A tile: 128 rows x 32 k = 1024 float4, 4/thread
        #pragma unroll
        for (int i = 0; i < 4; ++i) {
            int fid = t + 256 * i;
            int row = fid >> 3, k4 = fid & 7;
            float4 v = *(const float4*)&x[(size_t)(bm + row) * INF_ + ks + k4 * 4];
            As[k4 * 4 + 0][row] = v.x;
            As[k4 * 4 + 1][row] = v.y;
            As[k4 * 4 + 2][row] = v.z;
            As[k4 * 4 + 3][row] = v.w;
        }
        // load B tile: 32 k x 128 n
        #pragma unroll
        for (int i = 0; i < 4; ++i) {
            int fid = t + 256 * i;
            int k = fid >> 5, n4 = fid & 31;
            *(float4*)&Bs[k][n4 * 4] = *(const float4*)&W[(ks + k) * HH + bn + n4 * 4];
        }
        __syncthreads();

        #pragma unroll
        for (int k = 0; k < 32; ++k) {
            float a[8], b[8];
            *(float4*)&a[0] = *(float4*)&As[k][tr * 8];
            *(float4*)&a[4] = *(float4*)&As[k][tr * 8 + 4];
            *(float4*)&b[0] = *(float4*)&Bs[k][tc * 8];
            *(float4*)&b[4] = *(float4*)&Bs[k][tc * 8 + 4];
            #pragma unroll
            for (int i = 0; i < 8; ++i)
                #pragma unroll
                for (int j = 0; j < 8; ++j)
                    acc[i][j] += a[i] * b[j];
        }
        __syncthreads();
    }

    // epilogue: + cadd[m%100, col], convert to bf16, 16B stores
    #pragma unroll
    for (int i = 0; i < 8; ++i) {
        int m = bm + tr * 8 + i;
        int nidx = m % NN;
        const float* crow = &cb[nidx * HH + bn + tc * 8];
        union { __hip_bfloat16 h[8]; float4 v; } u;
        #pragma unroll
        for (int j = 0; j < 8; ++j)
            u.h[j] = __float2bfloat16(acc[i][j] + crow[j]);
        *reinterpret_cast<float4*>(&out[(size_t)m * HH + bn + tc * 8]) = u.v;
    }
}

// ---------------------------------------------------------------------------
// Kernel F: per-batch GATv2 softmax + pooled + FC.
//  Edges: dst j receives from {j-1, j, j+1} (valid only).
//  logit = att . leaky_relu(xl[src] + xr[dst])
//  pooled[h] = sum_i w_i * xl[i,h] + 100*bias[h],  w_i = a0[i]+am[i+1]+ap[i-1]
//  out[b,c] = pooled . W_fc[:,c] + b_fc[c]
// grid: 2048 blocks x 256 threads. xl[b] staged in LDS (bf16, 51.2 KB).
// ---------------------------------------------------------------------------
__global__ __launch_bounds__(256) void gat_pool_k(
    const __hip_bfloat16* __restrict__ xl, const __hip_bfloat16* __restrict__ xr,
    const float* __restrict__ att, const float* __restrict__ bias,
    const float* __restrict__ Wfc, const float* __restrict__ bfc,
    float* __restrict__ out)
{
    int b = blockIdx.x;
    int t = threadIdx.x;
    __shared__ __hip_bfloat16 sxl[NN * HH];   // 51200 B
    __shared__ float am[NN], a0s[NN], ap[NN], wv[NN];
    __shared__ float partial[4][3];

    const __hip_bfloat16* xlb = xl + (size_t)b * (NN * HH);
    const __hip_bfloat16* xrb = xr + (size_t)b * (NN * HH);

    // phase A: load xl[b] into LDS. 25600 bf16 = 3200 x 16B
    for (int i = t; i < 3200; i += 256) {
        *reinterpret_cast<float4*>(&sxl[i * 8]) =
            *reinterpret_cast<const float4*>(&xlb[i * 8]);
    }
    __syncthreads();

    int wave = t >> 6, lane = t & 63;
    float4 av = *reinterpret_cast<const float4*>(&att[2 * HH + lane * 4]);

    // phase B: logits + per-dst softmax (one dst j per wave iteration)
    for (int j = wave; j < NN; j += 4) {
        ushort4 ur = *reinterpret_cast<const ushort4*>(&xrb[j * HH + lane * 4]);
        float yr0 = bf2f(ur.x), yr1 = bf2f(ur.y), yr2 = bf2f(ur.z), yr3 = bf2f(ur.w);
        float lg[3];
        #pragma unroll
        for (int s = 0; s < 3; ++s) {
            int src = j + s - 1;
            float sum = -1e30f;
            if (src >= 0 && src < NN) {           // wave-uniform condition
                ushort4 ul = *reinterpret_cast<const ushort4*>(&sxl[src * HH + lane * 4]);
                float v0 = bf2f(ul.x) + yr0;
                float v1 = bf2f(ul.y) + yr1;
                float v2 = bf2f(ul.z) + yr2;
                float v3 = bf2f(ul.w) + yr3;
                v0 = (v0 > 0.f) ? v0 : 0.2f * v0;
                v1 = (v1 > 0.f) ? v1 : 0.2f * v1;
                v2 = (v2 > 0.f) ? v2 : 0.2f * v2;
                v3 = (v3 > 0.f) ? v3 : 0.2f * v3;
                sum = av.x * v0 + av.y * v1 + av.z * v2 + av.w * v3;
                #pragma unroll
                for (int off = 32; off; off >>= 1)
                    sum += __shfl_down(sum, off, 64);
            }
            lg[s] = sum;
        }
        if (lane == 0) {
            float mx = fmaxf(fmaxf(lg[0], lg[1]), lg[2]);
            float e0 = (j >= 1)      ? expf(lg[0] - mx) : 0.f;
            float e1 =                 expf(lg[1] - mx);
            float e2 = (j <= NN - 2) ? expf(lg[2] - mx) : 0.f;
            float inv = 1.f / (e0 + e1 + e2);
            am[j] = e0 * inv; a0s[j] = e1 * inv; ap[j] = e2 * inv;
        }
    }
    __syncthreads();

    // phase C: per-src total weight
    if (t < NN) {
        float v = a0s[t];
        if (t < NN - 1) v += am[t + 1];
        if (t > 0)      v += ap[t - 1];
        wv[t] = v;
    }
    __syncthreads();

    // phase D: pooled[h=t] = sum_i wv[i]*xl[i,t] + 100*bias[t]
    float pooled = 100.f * bias[2 * HH + t];
    for (int i = 0; i < NN; ++i) {
        unsigned short u = *reinterpret_cast<const unsigned short*>(&sxl[i * HH + t]);
        pooled += wv[i] * bf2f(u);
    }

    // phase E: FC [256,3] + block reduce
    float p0 = pooled * Wfc[t * 3 + 0];
    float p1 = pooled * Wfc[t * 3 + 1];
    float p2 = pooled * Wfc[t * 3 + 2];
    #pragma unroll
    for (int off = 32; off; off >>= 1) {
        p0 += __shfl_down(p0, off, 64);
        p1 += __shfl_down(p1, off, 64);
        p2 += __shfl_down(p2, off, 64);
    }
    if (lane == 0) { partial[wave][0] = p0; partial[wave][1] = p1; partial[wave][2] = p2; }
    __syncthreads();
    if (t < CC) {
        out[(size_t)b * CC + t] =
            partial[0][t] + partial[1][t] + partial[2][t] + partial[3][t] + bfc[t];
    }
}

// ---------------------------------------------------------------------------
extern "C" void kernel_launch(void* const* d_in, const int* in_sizes, int n_in,
                              void* d_out, int out_size, void* d_ws, size_t ws_size,
                              hipStream_t stream) {
    const float* x     = (const float*)d_in[0];
    const float* W_exp = (const float*)d_in[1];
    const float* b_exp = (const float*)d_in[2];
    const float* W_l   = (const float*)d_in[3];
    const float* b_l   = (const float*)d_in[4];
    const float* W_r   = (const float*)d_in[5];
    const float* b_r   = (const float*)d_in[6];
    const float* att   = (const float*)d_in[7];
    const float* bias  = (const float*)d_in[8];
    const float* W_fc  = (const float*)d_in[9];
    const float* b_fc  = (const float*)d_in[10];
    float* out = (float*)d_out;

    // workspace layout
    char* ws = (char*)d_ws;
    const size_t XL_BYTES = (size_t)MM * HH * sizeof(__hip_bfloat16);  // 104857600
    __hip_bfloat16* xl = (__hip_bfloat16*)ws;
    __hip_bfloat16* xr = (__hip_bfloat16*)(ws + XL_BYTES);
    float* Wcomb = (float*)(ws + 2 * XL_BYTES);                        // 2*64*256 f32
    float* cadd  = (float*)(ws + 2 * XL_BYTES + 2 * INF_ * HH * sizeof(float));

    precompute_k<<<dim3(164, 2), 256, 0, stream>>>(W_exp, b_exp, W_l, b_l, W_r, b_r,
                                                   Wcomb, cadd);
    gemm_xlr_k<<<dim3(MM / G_BM, HH / G_BN, 2), 256, 0, stream>>>(x, Wcomb, cadd, xl, xr);
    gat_pool_k<<<BB, 256, 0, stream>>>(xl, xr, att, bias, W_fc, b_fc, out);
}

// Round 2
// 228.007 us; speedup vs baseline: 1.3322x; 1.3322x over previous
//
#include <hip/hip_runtime.h>
#include <hip/hip_bf16.h>

// Problem constants
#define BB 2048
#define NN 100
#define INF_ 64
#define HH 256
#define CC 3
#define MM 204800

typedef __attribute__((ext_vector_type(8))) short s8v;   // 8 bf16 (4 VGPRs)
typedef __attribute__((ext_vector_type(4))) float f4v;   // 4 fp32 acc

static __device__ __forceinline__ float bf2f(unsigned short u) {
    union { float f; unsigned int i; } c;
    c.i = ((unsigned int)u) << 16;
    return c.f;
}
static __device__ __forceinline__ unsigned short f2bf(float f) {
    union { float f; unsigned int u; } c; c.f = f;
    unsigned int r = c.u + 0x7FFF + ((c.u >> 16) & 1);   // RNE, finite inputs
    return (unsigned short)(r >> 16);
}

// ---------------------------------------------------------------------------
// Kernel P: Wcomb[z][64][256] = W_exp @ W_{l,r}[2] (f32)
//           cadd[z][100][256] = (b_exp + pe[n]) @ W_{l,r}[2] + b_{l,r}[2] (f32)
// ---------------------------------------------------------------------------
__global__ __launch_bounds__(256) void precompute_k(
    const float* __restrict__ W_exp, const float* __restrict__ b_exp,
    const float* __restrict__ W_l, const float* __restrict__ b_l,
    const float* __restrict__ W_r, const float* __restrict__ b_r,
    float* __restrict__ Wcomb, float* __restrict__ cadd)
{
    int r = blockIdx.x;           // 0..163
    int z = blockIdx.y;           // 0 = l, 1 = r
    int t = threadIdx.x;          // output col
    const float* Wg = (z ? W_r : W_l) + 2 * HH * HH;  // layer 2
    const float* bg = (z ? b_r : b_l) + 2 * HH;

    __shared__ float sa[HH];
    float a;
    if (r < INF_) {
        a = W_exp[r * HH + t];
    } else {
        int n = r - INF_;
        float div = expf((float)(t & 254) * (-0.03597789207803f));
        float ang = (float)n * div;
        a = b_exp[t] + ((t & 1) ? cosf(ang) : sinf(ang));
    }
    sa[t] = a;
    __syncthreads();

    float acc = 0.f;
    #pragma unroll 8
    for (int h = 0; h < HH; ++h)
        acc += sa[h] * Wg[h * HH + t];

    if (r < INF_) Wcomb[(z * INF_ + r) * HH + t] = acc;
    else          cadd[(z * NN + (r - INF_)) * HH + t] = acc + bg[t];
}

// ---------------------------------------------------------------------------
// Kernel R: rearrange Wcomb/cadd into MFMA fragment layouts (bf16).
//  WF[z][nt:16][ks:2][lane:64][j:8] : Wcomb[z][k][n],
//      k = ks*32 + 4*(lane>>4) + (j&3) + 16*(j>>2),  n = nt*16 + (lane&15)
//  CF[z][mt:7][nt:16][lane:64][r:4] : cadd[z][row][col],
//      row = mt*16 + (lane>>4)*4 + r, col = nt*16 + (lane&15)  (row>=100 -> 0)
// 352 blocks x 256 = 90112 = 32768 + 57344 threads.
// ---------------------------------------------------------------------------
#define N_WF 32768
#define N_CF 57344

__global__ __launch_bounds__(256) void rearrange_k(
    const float* __restrict__ Wcomb, const float* __restrict__ cadd,
    unsigned short* __restrict__ WF, unsigned short* __restrict__ CF)
{
    int i = blockIdx.x * 256 + threadIdx.x;
    if (i < N_WF) {
        int j = i & 7, lane = (i >> 3) & 63, ks = (i >> 9) & 1;
        int nt = (i >> 10) & 15, z = (i >> 14) & 1;
        int k = ks * 32 + 4 * (lane >> 4) + (j & 3) + 16 * (j >> 2);
        int n = nt * 16 + (lane & 15);
        WF[i] = f2bf(Wcomb[(z * INF_ + k) * HH + n]);
    } else {
        int i2 = i - N_WF;
        int reg = i2 & 3, lane = (i2 >> 2) & 63, nt = (i2 >> 8) & 15;
        int rest = i2 >> 12;               // 0..13
        int mt = rest % 7, z = rest / 7;
        int row = mt * 16 + (lane >> 4) * 4 + reg;
        int col = nt * 16 + (lane & 15);
        CF[i2] = f2bf(row < NN ? cadd[(z * NN + row) * HH + col] : 0.f);
    }
}

// ---------------------------------------------------------------------------
// Kernel F (fused): per batch b, 512 threads (8 waves):
//  1. A-frags: x[b] (100x64 f32) -> bf16 MFMA fragments in registers
//  2. xl = A @ WF_l + CF_l ; xr likewise  (mfma 16x16x32, acc fp32) -> LDS bf16
//  3. GATv2 logits/softmax for chain+self edges, pooled sum, FC -> out[b][3]
// ---------------------------------------------------------------------------
#define SRD 264   // padded LDS row stride (bf16 elems)

__global__ __launch_bounds__(512) void fused_k(
    const float* __restrict__ x,
    const unsigned short* __restrict__ WF, const unsigned short* __restrict__ CF,
    const float* __restrict__ att, const float* __restrict__ bias,
    const float* __restrict__ Wfc, const float* __restrict__ bfc,
    float* __restrict__ out)
{
    __shared__ unsigned short sxl[NN * SRD];   // 52800 B
    __shared__ unsigned short sxr[NN * SRD];   // 52800 B
    __shared__ float am[NN], a0s[NN], ap[NN], wv[NN];
    __shared__ float partial[4][3];

    int b = blockIdx.x, t = threadIdx.x;
    int wave = t >> 6, lane = t & 63, g = lane >> 4, li = lane & 15;

    // ---- phase 1: A fragments from global x ----
    s8v afr[7][2];
    const float* xb = x + (size_t)b * (NN * INF_);
    #pragma unroll
    for (int mt = 0; mt < 7; ++mt) {
        int m = mt * 16 + li;
        bool valid = (m < NN);
        const float* xrow = xb + (size_t)(valid ? m : NN - 1) * INF_;
        #pragma unroll
        for (int ks = 0; ks < 2; ++ks) {
            float4 u = *(const float4*)&xrow[ks * 32 + 4 * g];
            float4 v = *(const float4*)&xrow[ks * 32 + 16 + 4 * g];
            if (!valid) { u.x=u.y=u.z=u.w=0.f; v=u; }
            s8v a;
            a[0]=(short)f2bf(u.x); a[1]=(short)f2bf(u.y);
            a[2]=(short)f2bf(u.z); a[3]=(short)f2bf(u.w);
            a[4]=(short)f2bf(v.x); a[5]=(short)f2bf(v.y);
            a[6]=(short)f2bf(v.z); a[7]=(short)f2bf(v.w);
            afr[mt][ks] = a;
        }
    }

    // ---- phase 2: MFMA GEMM + epilogue to LDS ----
    #pragma unroll
    for (int z = 0; z < 2; ++z) {
        unsigned short* dst = z ? sxr : sxl;
        #pragma unroll
        for (int ni = 0; ni < 2; ++ni) {
            int nt = wave * 2 + ni;
            const s8v* bp = (const s8v*)WF + ((size_t)(z * 16 + nt) * 2) * 64;
            s8v b0 = bp[lane];
            s8v b1 = bp[64 + lane];
            #pragma unroll
            for (int mt = 0; mt < 7; ++mt) {
                f4v c = {0.f, 0.f, 0.f, 0.f};
                c = __builtin_amdgcn_mfma_f32_16x16x32_bf16(afr[mt][0], b0, c, 0, 0, 0);
                c = __builtin_amdgcn_mfma_f32_16x16x32_bf16(afr[mt][1], b1, c, 0, 0, 0);
                union { ushort4 v; unsigned short s[4]; } cd;
                cd.v = *(const ushort4*)&CF[(((size_t)(z * 7 + mt) * 16 + nt) * 64 + lane) * 4];
                int col = nt * 16 + li;
                #pragma unroll
                for (int r = 0; r < 4; ++r) {
                    int row = mt * 16 + g * 4 + r;
                    if (row < NN)
                        dst[row * SRD + col] = f2bf(c[r] + bf2f(cd.s[r]));
                }
            }
        }
    }
    __syncthreads();

    // ---- phase 3: logits + per-dst softmax ----
    const float4 av = *(const float4*)&att[2 * HH + lane * 4];
    for (int j = wave; j < NN; j += 8) {
        union { ushort4 v; unsigned short s[4]; } ur;
        ur.v = *(const ushort4*)&sxr[j * SRD + lane * 4];
        float yr0 = bf2f(ur.s[0]), yr1 = bf2f(ur.s[1]);
        float yr2 = bf2f(ur.s[2]), yr3 = bf2f(ur.s[3]);
        float lg[3];
        #pragma unroll
        for (int s = 0; s < 3; ++s) {
            int src = j + s - 1;
            float sum = -1e30f;
            if (src >= 0 && src < NN) {           // wave-uniform
                union { ushort4 v; unsigned short s[4]; } ul;
                ul.v = *(const ushort4*)&sxl[src * SRD + lane * 4];
                float v0 = bf2f(ul.s[0]) + yr0;
                float v1 = bf2f(ul.s[1]) + yr1;
                float v2 = bf2f(ul.s[2]) + yr2;
                float v3 = bf2f(ul.s[3]) + yr3;
                v0 = (v0 > 0.f) ? v0 : 0.2f * v0;
                v1 = (v1 > 0.f) ? v1 : 0.2f * v1;
                v2 = (v2 > 0.f) ? v2 : 0.2f * v2;
                v3 = (v3 > 0.f) ? v3 : 0.2f * v3;
                sum = av.x * v0 + av.y * v1 + av.z * v2 + av.w * v3;
                #pragma unroll
                for (int off = 32; off; off >>= 1)
                    sum += __shfl_down(sum, off, 64);
            }
            lg[s] = sum;
        }
        if (lane == 0) {
            float mx = fmaxf(fmaxf(lg[0], lg[1]), lg[2]);
            float e0 = (j >= 1)      ? expf(lg[0] - mx) : 0.f;
            float e1 =                 expf(lg[1] - mx);
            float e2 = (j <= NN - 2) ? expf(lg[2] - mx) : 0.f;
            float inv = 1.f / (e0 + e1 + e2);
            am[j] = e0 * inv; a0s[j] = e1 * inv; ap[j] = e2 * inv;
        }
    }
    __syncthreads();

    // ---- phase 4: per-src total weight ----
    if (t < NN) {
        float v = a0s[t];
        if (t < NN - 1) v += am[t + 1];
        if (t > 0)      v += ap[t - 1];
        wv[t] = v;
    }
    __syncthreads();

    // ---- phase 5: pooled + FC ----
    if (t < HH) {
        float pooled = 100.f * bias[2 * HH + t];
        for (int i = 0; i < NN; ++i)
            pooled += wv[i] * bf2f(sxl[i * SRD + t]);

        float p0 = pooled * Wfc[t * 3 + 0];
        float p1 = pooled * Wfc[t * 3 + 1];
        float p2 = pooled * Wfc[t * 3 + 2];
        #pragma unroll
        for (int off = 32; off; off >>= 1) {
            p0 += __shfl_down(p0, off, 64);
            p1 += __shfl_down(p1, off, 64);
            p2 += __shfl_down(p2, off, 64);
        }
        if (lane == 0) { partial[wave][0] = p0; partial[wave][1] = p1; partial[wave][2] = p2; }
    }
    __syncthreads();
    if (t < CC) {
        out[(size_t)b * CC + t] =
            partial[0][t] + partial[1][t] + partial[2][t] + partial[3][t] + bfc[t];
    }
}

// ---------------------------------------------------------------------------
extern "C" void kernel_launch(void* const* d_in, const int* in_sizes, int n_in,
                              void* d_out, int out_size, void* d_ws, size_t ws_size,
                              hipStream_t stream) {
    const float* x     = (const float*)d_in[0];
    const float* W_exp = (const float*)d_in[1];
    const float* b_exp = (const float*)d_in[2];
    const float* W_l   = (const float*)d_in[3];
    const float* b_l   = (const float*)d_in[4];
    const float* W_r   = (const float*)d_in[5];
    const float* b_r   = (const float*)d_in[6];
    const float* att   = (const float*)d_in[7];
    const float* bias  = (const float*)d_in[8];
    const float* W_fc  = (const float*)d_in[9];
    const float* b_fc  = (const float*)d_in[10];
    float* out = (float*)d_out;

    // workspace layout (all 16B aligned)
    char* ws = (char*)d_ws;
    float* Wcomb = (float*)ws;                                   // 131072 B
    float* cadd  = (float*)(ws + 131072);                        // 204800 B
    unsigned short* WF = (unsigned short*)(ws + 131072 + 204800);          // 65536 B
    unsigned short* CF = (unsigned short*)(ws + 131072 + 204800 + 65536);  // 114688 B

    precompute_k<<<dim3(164, 2), 256, 0, stream>>>(W_exp, b_exp, W_l, b_l, W_r, b_r,
                                                   Wcomb, cadd);
    rearrange_k<<<352, 256, 0, stream>>>(Wcomb, cadd, WF, CF);
    fused_k<<<BB, 512, 0, stream>>>(x, WF, CF, att, bias, W_fc, b_fc, out);
}

// Round 3
// 211.677 us; speedup vs baseline: 1.4350x; 1.0771x over previous
//
#include <hip/hip_runtime.h>
#include <hip/hip_bf16.h>

// Problem constants
#define BB 2048
#define NN 100
#define INF_ 64
#define HH 256
#define CC 3

typedef __attribute__((ext_vector_type(8))) short s8v;   // 8 bf16 (4 VGPRs)
typedef __attribute__((ext_vector_type(4))) float f4v;   // 4 fp32 acc

static __device__ __forceinline__ float bf2f(unsigned short u) {
    union { float f; unsigned int i; } c;
    c.i = ((unsigned int)u) << 16;
    return c.f;
}
static __device__ __forceinline__ unsigned short f2bf(float f) {
    union { float f; unsigned int u; } c; c.f = f;
    unsigned int r = c.u + 0x7FFF + ((c.u >> 16) & 1);   // RNE, finite inputs
    return (unsigned short)(r >> 16);
}
static __device__ __forceinline__ float u2f_lo(unsigned int u) {
    union { float f; unsigned int i; } c; c.i = u << 16; return c.f;
}
static __device__ __forceinline__ float u2f_hi(unsigned int u) {
    union { float f; unsigned int i; } c; c.i = u & 0xffff0000u; return c.f;
}
// swizzled LDS element index: XOR byte-bits 4..6 == elem-bits 3..5 with row&7
static __device__ __forceinline__ int swzA(int row, int col) {   // [100][256]
    return (row * HH + col) ^ ((row & 7) << 3);
}
static __device__ __forceinline__ int swzR(int row, int col) {   // [100][128]
    return (row * 128 + col) ^ ((row & 7) << 3);
}

// ---------------------------------------------------------------------------
// Kernel P: Wcomb[z][64][256] = W_exp @ W_{l,r}[2] (f32)
//           cadd[z][100][256] = (b_exp + pe[n]) @ W_{l,r}[2] + b_{l,r}[2] (f32)
// ---------------------------------------------------------------------------
__global__ __launch_bounds__(256) void precompute_k(
    const float* __restrict__ W_exp, const float* __restrict__ b_exp,
    const float* __restrict__ W_l, const float* __restrict__ b_l,
    const float* __restrict__ W_r, const float* __restrict__ b_r,
    float* __restrict__ Wcomb, float* __restrict__ cadd)
{
    int r = blockIdx.x;           // 0..163
    int z = blockIdx.y;           // 0 = l, 1 = r
    int t = threadIdx.x;          // output col
    const float* Wg = (z ? W_r : W_l) + 2 * HH * HH;  // layer 2
    const float* bg = (z ? b_r : b_l) + 2 * HH;

    __shared__ float sa[HH];
    float a;
    if (r < INF_) {
        a = W_exp[r * HH + t];
    } else {
        int n = r - INF_;
        float div = expf((float)(t & 254) * (-0.03597789207803f));
        float ang = (float)n * div;
        a = b_exp[t] + ((t & 1) ? cosf(ang) : sinf(ang));
    }
    sa[t] = a;
    __syncthreads();

    float acc = 0.f;
    #pragma unroll 8
    for (int h = 0; h < HH; ++h)
        acc += sa[h] * Wg[h * HH + t];

    if (r < INF_) Wcomb[(z * INF_ + r) * HH + t] = acc;
    else          cadd[(z * NN + (r - INF_)) * HH + t] = acc + bg[t];
}

// ---------------------------------------------------------------------------
// Kernel R: rearrange Wcomb/cadd into MFMA fragment layouts (bf16).
//  WF[z][nt:16][ks:2][lane:64][j:8] : Wcomb[z][k][n],
//      k = ks*32 + 4*(lane>>4) + (j&3) + 16*(j>>2),  n = nt*16 + (lane&15)
//  CF[z][mt:7][nt:16][lane:64][r:4] : cadd[z][row][col],
//      row = mt*16 + (lane>>4)*4 + r, col = nt*16 + (lane&15)  (row>=100 -> 0)
// ---------------------------------------------------------------------------
#define N_WF 32768
#define N_CF 57344

__global__ __launch_bounds__(256) void rearrange_k(
    const float* __restrict__ Wcomb, const float* __restrict__ cadd,
    unsigned short* __restrict__ WF, unsigned short* __restrict__ CF)
{
    int i = blockIdx.x * 256 + threadIdx.x;
    if (i < N_WF) {
        int j = i & 7, lane = (i >> 3) & 63, ks = (i >> 9) & 1;
        int nt = (i >> 10) & 15, z = (i >> 14) & 1;
        int k = ks * 32 + 4 * (lane >> 4) + (j & 3) + 16 * (j >> 2);
        int n = nt * 16 + (lane & 15);
        WF[i] = f2bf(Wcomb[(z * INF_ + k) * HH + n]);
    } else {
        int i2 = i - N_WF;
        int reg = i2 & 3, lane = (i2 >> 2) & 63, nt = (i2 >> 8) & 15;
        int rest = i2 >> 12;               // 0..13
        int mt = rest % 7, z = rest / 7;
        int row = mt * 16 + (lane >> 4) * 4 + reg;
        int col = nt * 16 + (lane & 15);
        CF[i2] = f2bf(row < NN ? cadd[(z * NN + row) * HH + col] : 0.f);
    }
}

// ---------------------------------------------------------------------------
// Kernel F (fused): one block per batch, 512 threads (8 waves), 2 blocks/CU.
//  Per h-half (128 cols): MFMA -> xl (persistent full) / xr (half chunk) in
//  LDS; edge-per-thread logit accumulation (no shuffles). Then softmax/wv,
//  vectorized pooled, FC.
// ---------------------------------------------------------------------------
__global__ __launch_bounds__(512, 4) void fused_k(
    const float* __restrict__ x,
    const unsigned short* __restrict__ WF, const unsigned short* __restrict__ CF,
    const float* __restrict__ att, const float* __restrict__ bias,
    const float* __restrict__ Wfc, const float* __restrict__ bfc,
    float* __restrict__ out)
{
    __shared__ unsigned short sxl[NN * HH];    // 51200 B (swizzled)
    __shared__ unsigned short sxr[NN * 128];   // 25600 B (swizzled, per-half)
    __shared__ float lg[300];
    __shared__ float wv[NN];
    __shared__ float partial[4][3];

    int b = blockIdx.x, t = threadIdx.x;
    int wave = t >> 6, lane = t & 63, g = lane >> 4, li = lane & 15;

    // ---- phase 1: A fragments from global x ----
    s8v afr[7][2];
    const float* xb = x + (size_t)b * (NN * INF_);
    #pragma unroll
    for (int mt = 0; mt < 7; ++mt) {
        int m = mt * 16 + li;
        bool valid = (m < NN);
        const float* xrow = xb + (size_t)(valid ? m : NN - 1) * INF_;
        #pragma unroll
        for (int ks = 0; ks < 2; ++ks) {
            float4 u = *(const float4*)&xrow[ks * 32 + 4 * g];
            float4 v = *(const float4*)&xrow[ks * 32 + 16 + 4 * g];
            if (!valid) { u.x=u.y=u.z=u.w=0.f; v=u; }
            s8v a;
            a[0]=(short)f2bf(u.x); a[1]=(short)f2bf(u.y);
            a[2]=(short)f2bf(u.z); a[3]=(short)f2bf(u.w);
            a[4]=(short)f2bf(v.x); a[5]=(short)f2bf(v.y);
            a[6]=(short)f2bf(v.z); a[7]=(short)f2bf(v.w);
            afr[mt][ks] = a;
        }
    }

    // edge identity for phase 3 (thread t < 300 owns edge t)
    int src = 0, dst = 0; bool evalid = false;
    if (t < 300) {
        src = t / 3;
        int d = t - 3 * src - 1;
        dst = src + d;
        evalid = (dst >= 0 && dst < NN);
    }
    float accv = 0.f, acca = 0.f;
    const float* attp = att + 2 * HH;

    #pragma unroll
    for (int half = 0; half < 2; ++half) {
        // ---- phase 2: MFMA + epilogue to LDS (xl full cols, xr half chunk) ----
        #pragma unroll
        for (int z = 0; z < 2; ++z) {
            int nt = half * 8 + wave;
            const s8v* bp = (const s8v*)WF + ((size_t)(z * 16 + nt) * 2) * 64;
            s8v b0 = bp[lane];
            s8v b1 = bp[64 + lane];
            #pragma unroll
            for (int mt = 0; mt < 7; ++mt) {
                f4v c = {0.f, 0.f, 0.f, 0.f};
                c = __builtin_amdgcn_mfma_f32_16x16x32_bf16(afr[mt][0], b0, c, 0, 0, 0);
                c = __builtin_amdgcn_mfma_f32_16x16x32_bf16(afr[mt][1], b1, c, 0, 0, 0);
                union { ushort4 v; unsigned short s[4]; } cd;
                cd.v = *(const ushort4*)&CF[(((size_t)(z * 7 + mt) * 16 + nt) * 64 + lane) * 4];
                #pragma unroll
                for (int r = 0; r < 4; ++r) {
                    int row = mt * 16 + g * 4 + r;
                    if (row < NN) {
                        unsigned short val = f2bf(c[r] + bf2f(cd.s[r]));
                        if (z == 0) sxl[swzA(row, nt * 16 + li)] = val;
                        else        sxr[swzR(row, wave * 16 + li)] = val;
                    }
                }
            }
        }
        __syncthreads();

        // ---- phase 3: edge-per-thread logit accumulation over this half ----
        if (evalid) {
            #pragma unroll 4
            for (int hb = 0; hb < 16; ++hb) {
                int h = hb * 8;
                uint4 ua = *(const uint4*)&sxl[swzA(src, half * 128 + h)];
                uint4 ub = *(const uint4*)&sxr[swzR(dst, h)];
                const float* ap = attp + half * 128 + h;   // wave-uniform
                #define PROC(UL, UR, A0, A1) { \
                    float v0 = u2f_lo(UL) + u2f_lo(UR); \
                    float v1 = u2f_hi(UL) + u2f_hi(UR); \
                    accv = fmaf(A0, v0, accv); acca = fmaf(A0, fabsf(v0), acca); \
                    accv = fmaf(A1, v1, accv); acca = fmaf(A1, fabsf(v1), acca); }
                PROC(ua.x, ub.x, ap[0], ap[1]);
                PROC(ua.y, ub.y, ap[2], ap[3]);
                PROC(ua.z, ub.z, ap[4], ap[5]);
                PROC(ua.w, ub.w, ap[6], ap[7]);
                #undef PROC
            }
        }
        __syncthreads();
    }

    // leaky_relu(v) = max(v,0) + 0.2*min(v,0) = 0.6*v + 0.4*|v|
    if (t < 300) lg[t] = evalid ? (0.6f * accv + 0.4f * acca) : -1e30f;
    __syncthreads();

    // ---- phase 4: wv[i] = sum over dst j in {i-1,i,i+1} of alpha(i->j) ----
    if (t < NN) {
        int i = t;
        float w = 0.f;
        #pragma unroll
        for (int dj = -1; dj <= 1; ++dj) {
            int j = i + dj;
            if (j < 0 || j >= NN) continue;
            float l0 = (j - 1 >= 0) ? lg[3 * (j - 1) + 2] : -1e30f;  // j-1 -> j
            float l1 = lg[3 * j + 1];                                 // j   -> j
            float l2 = (j + 1 < NN) ? lg[3 * (j + 1) + 0] : -1e30f;  // j+1 -> j
            float mx = fmaxf(fmaxf(l0, l1), l2);
            float den = expf(l0 - mx) + expf(l1 - mx) + expf(l2 - mx);
            float myl = lg[3 * i + dj + 1];
            w += expf(myl - mx) / den;
        }
        wv[i] = w;
    }
    __syncthreads();

    // ---- phase 5: pooled[col] partials per wave (rows split across waves) ----
    {
        float pa0 = 0.f, pa1 = 0.f, pa2 = 0.f, pa3 = 0.f;
        int r0 = wave * 13;
        int r1 = (r0 + 13 < NN) ? r0 + 13 : NN;
        int c0 = lane * 4;
        for (int row = r0; row < r1; ++row) {
            float wr = wv[row];
            uint2 u = *(const uint2*)&sxl[swzA(row, c0)];
            pa0 = fmaf(wr, u2f_lo(u.x), pa0);
            pa1 = fmaf(wr, u2f_hi(u.x), pa1);
            pa2 = fmaf(wr, u2f_lo(u.y), pa2);
            pa3 = fmaf(wr, u2f_hi(u.y), pa3);
        }
        float* pp = (float*)sxr;   // reuse: 8 waves x 256 cols f32 = 8 KB
        float4 pv = { pa0, pa1, pa2, pa3 };
        *(float4*)&pp[wave * HH + c0] = pv;
    }
    __syncthreads();

    // ---- phase 6: FC [256,3] + block reduce ----
    if (t < HH) {
        const float* pp = (const float*)sxr;
        float pooled = 100.f * bias[2 * HH + t];
        #pragma unroll
        for (int w = 0; w < 8; ++w) pooled += pp[w * HH + t];

        float p0 = pooled * Wfc[t * 3 + 0];
        float p1 = pooled * Wfc[t * 3 + 1];
        float p2 = pooled * Wfc[t * 3 + 2];
        #pragma unroll
        for (int off = 32; off; off >>= 1) {
            p0 += __shfl_down(p0, off, 64);
            p1 += __shfl_down(p1, off, 64);
            p2 += __shfl_down(p2, off, 64);
        }
        if (lane == 0) { partial[wave][0] = p0; partial[wave][1] = p1; partial[wave][2] = p2; }
    }
    __syncthreads();
    if (t < CC) {
        out[(size_t)b * CC + t] =
            partial[0][t] + partial[1][t] + partial[2][t] + partial[3][t] + bfc[t];
    }
}

// ---------------------------------------------------------------------------
extern "C" void kernel_launch(void* const* d_in, const int* in_sizes, int n_in,
                              void* d_out, int out_size, void* d_ws, size_t ws_size,
                              hipStream_t stream) {
    const float* x     = (const float*)d_in[0];
    const float* W_exp = (const float*)d_in[1];
    const float* b_exp = (const float*)d_in[2];
    const float* W_l   = (const float*)d_in[3];
    const float* b_l   = (const float*)d_in[4];
    const float* W_r   = (const float*)d_in[5];
    const float* b_r   = (const float*)d_in[6];
    const float* att   = (const float*)d_in[7];
    const float* bias  = (const float*)d_in[8];
    const float* W_fc  = (const float*)d_in[9];
    const float* b_fc  = (const float*)d_in[10];
    float* out = (float*)d_out;

    // workspace layout (16B aligned)
    char* ws = (char*)d_ws;
    float* Wcomb = (float*)ws;                                             // 131072 B
    float* cadd  = (float*)(ws + 131072);                                  // 204800 B
    unsigned short* WF = (unsigned short*)(ws + 131072 + 204800);          // 65536 B
    unsigned short* CF = (unsigned short*)(ws + 131072 + 204800 + 65536);  // 114688 B

    precompute_k<<<dim3(164, 2), 256, 0, stream>>>(W_exp, b_exp, W_l, b_l, W_r, b_r,
                                                   Wcomb, cadd);
    rearrange_k<<<352, 256, 0, stream>>>(Wcomb, cadd, WF, CF);
    fused_k<<<BB, 512, 0, stream>>>(x, WF, CF, att, bias, W_fc, b_fc, out);
}

// Round 4
// 121.794 us; speedup vs baseline: 2.4940x; 1.7380x over previous
//
#include <hip/hip_runtime.h>
#include <hip/hip_bf16.h>

// Problem constants
#define BB 2048
#define NN 100
#define INF_ 64
#define HH 256
#define CC 3

typedef __attribute__((ext_vector_type(8))) short s8v;   // 8 bf16 (4 VGPRs)
typedef __attribute__((ext_vector_type(4))) float f4v;   // 4 fp32 acc

static __device__ __forceinline__ float bf2f(unsigned short u) {
    union { float f; unsigned int i; } c;
    c.i = ((unsigned int)u) << 16;
    return c.f;
}
static __device__ __forceinline__ unsigned short f2bf(float f) {
    union { float f; unsigned int u; } c; c.f = f;
    unsigned int r = c.u + 0x7FFF + ((c.u >> 16) & 1);   // RNE, finite inputs
    return (unsigned short)(r >> 16);
}
static __device__ __forceinline__ float u2f_lo(unsigned int u) {
    union { float f; unsigned int i; } c; c.i = u << 16; return c.f;
}
static __device__ __forceinline__ float u2f_hi(unsigned int u) {
    union { float f; unsigned int i; } c; c.i = u & 0xffff0000u; return c.f;
}
// swizzled LDS element index: XOR elem-bits 3..5 with row&7 (byte bits 4..6)
static __device__ __forceinline__ int swzA(int row, int col) {   // [100][256]
    return (row * HH + col) ^ ((row & 7) << 3);
}
static __device__ __forceinline__ int swzQ(int row, int col) {   // [100][64]
    return (row * 64 + col) ^ ((row & 7) << 3);
}

// ---------------------------------------------------------------------------
// Kernel P: Wcomb[z][64][256] = W_exp @ W_{l,r}[2] (f32)
//           cadd[z][100][256] = (b_exp + pe[n]) @ W_{l,r}[2] + b_{l,r}[2] (f32)
// ---------------------------------------------------------------------------
__global__ __launch_bounds__(256) void precompute_k(
    const float* __restrict__ W_exp, const float* __restrict__ b_exp,
    const float* __restrict__ W_l, const float* __restrict__ b_l,
    const float* __restrict__ W_r, const float* __restrict__ b_r,
    float* __restrict__ Wcomb, float* __restrict__ cadd)
{
    int r = blockIdx.x;           // 0..163
    int z = blockIdx.y;           // 0 = l, 1 = r
    int t = threadIdx.x;          // output col
    const float* Wg = (z ? W_r : W_l) + 2 * HH * HH;  // layer 2
    const float* bg = (z ? b_r : b_l) + 2 * HH;

    __shared__ float sa[HH];
    float a;
    if (r < INF_) {
        a = W_exp[r * HH + t];
    } else {
        int n = r - INF_;
        float div = expf((float)(t & 254) * (-0.03597789207803f));
        float ang = (float)n * div;
        a = b_exp[t] + ((t & 1) ? cosf(ang) : sinf(ang));
    }
    sa[t] = a;
    __syncthreads();

    float acc = 0.f;
    #pragma unroll 8
    for (int h = 0; h < HH; ++h)
        acc += sa[h] * Wg[h * HH + t];

    if (r < INF_) Wcomb[(z * INF_ + r) * HH + t] = acc;
    else          cadd[(z * NN + (r - INF_)) * HH + t] = acc + bg[t];
}

// ---------------------------------------------------------------------------
// Kernel R: rearrange Wcomb/cadd into MFMA fragment layouts (bf16).
//  WF[z][nt:16][ks:2][lane:64][j:8] : Wcomb[z][k][n],
//      k = ks*32 + 4*(lane>>4) + (j&3) + 16*(j>>2),  n = nt*16 + (lane&15)
//  CF[z][mt:7][nt:16][lane:64][r:4] : cadd[z][row][col],
//      row = mt*16 + (lane>>4)*4 + r, col = nt*16 + (lane&15)  (row>=100 -> 0)
// ---------------------------------------------------------------------------
#define N_WF 32768
#define N_CF 57344

__global__ __launch_bounds__(256) void rearrange_k(
    const float* __restrict__ Wcomb, const float* __restrict__ cadd,
    unsigned short* __restrict__ WF, unsigned short* __restrict__ CF)
{
    int i = blockIdx.x * 256 + threadIdx.x;
    if (i < N_WF) {
        int j = i & 7, lane = (i >> 3) & 63, ks = (i >> 9) & 1;
        int nt = (i >> 10) & 15, z = (i >> 14) & 1;
        int k = ks * 32 + 4 * (lane >> 4) + (j & 3) + 16 * (j >> 2);
        int n = nt * 16 + (lane & 15);
        WF[i] = f2bf(Wcomb[(z * INF_ + k) * HH + n]);
    } else {
        int i2 = i - N_WF;
        int reg = i2 & 3, lane = (i2 >> 2) & 63, nt = (i2 >> 8) & 15;
        int rest = i2 >> 12;               // 0..13
        int mt = rest % 7, z = rest / 7;
        int row = mt * 16 + (lane >> 4) * 4 + reg;
        int col = nt * 16 + (lane & 15);
        CF[i2] = f2bf(row < NN ? cadd[(z * NN + row) * HH + col] : 0.f);
    }
}

// ---------------------------------------------------------------------------
// Kernel F (fused): one block per batch, 512 threads (8 waves), 2 blocks/CU.
//  Phase 1: x[b] -> LDS in A-fragment order ([mt][ks][lane][8] bf16).
//  Quarter loop (64 output cols each): waves 0-3 MFMA xl quarter, waves 4-7
//  MFMA xr quarter (A-frags via ds_read_b128, 2-instr live range -> no spill);
//  then edge-per-thread logit accumulation over the quarter.
//  Tail: softmax/wv, vectorized pooled, FC. lg/wv/partial alias dead sxs.
// ---------------------------------------------------------------------------
__global__ __launch_bounds__(512, 4) void fused_k(
    const float* __restrict__ x,
    const unsigned short* __restrict__ WF, const unsigned short* __restrict__ CF,
    const float* __restrict__ att, const float* __restrict__ bias,
    const float* __restrict__ Wfc, const float* __restrict__ bfc,
    float* __restrict__ out)
{
    __shared__ unsigned short sxl[NN * HH];    // 51200 B (swizzled, persistent)
    __shared__ unsigned short sxr[NN * 64];    // 12800 B (swizzled, per-quarter)
    __shared__ unsigned short sxs[896 * 8];    // 14336 B A-frags; later lg/wv/partial

    int b = blockIdx.x, t = threadIdx.x;
    int wave = t >> 6, lane = t & 63, g = lane >> 4, li = lane & 15;

    // ---- phase 1: stage x[b] as bf16 A-fragments in LDS ----
    const float* xb = x + (size_t)b * (NN * INF_);
    for (int s = t; s < 896; s += 512) {
        int sl = s & 63;            // fragment lane
        int ks = (s >> 6) & 1;
        int mt = s >> 7;
        int m  = mt * 16 + (sl & 15);
        int gg = sl >> 4;
        s8v a = (s8v){0,0,0,0,0,0,0,0};
        if (m < NN) {
            float4 u = *(const float4*)&xb[m * INF_ + ks * 32 + 4 * gg];
            float4 v = *(const float4*)&xb[m * INF_ + ks * 32 + 16 + 4 * gg];
            a[0]=(short)f2bf(u.x); a[1]=(short)f2bf(u.y);
            a[2]=(short)f2bf(u.z); a[3]=(short)f2bf(u.w);
            a[4]=(short)f2bf(v.x); a[5]=(short)f2bf(v.y);
            a[6]=(short)f2bf(v.z); a[7]=(short)f2bf(v.w);
        }
        *(s8v*)&sxs[s * 8] = a;
    }

    // edge identity for phase 3 (thread t < 300 owns edge t)
    int src = 0, dst = 0; bool evalid = false;
    if (t < 300) {
        src = t / 3;
        int d = t - 3 * src - 1;
        dst = src + d;
        evalid = (dst >= 0 && dst < NN);
    }
    float accv = 0.f, acca = 0.f;
    const float* attp = att + 2 * HH;

    int z = wave >> 2;                       // waves 0-3: xl, waves 4-7: xr
    __syncthreads();                         // sxs ready

    for (int q = 0; q < 4; ++q) {
        // ---- phase 2: MFMA quarter (4 nt tiles per z) ----
        int nt = q * 4 + (wave & 3);
        const s8v* bp = (const s8v*)WF + ((size_t)(z * 16 + nt) * 2) * 64;
        s8v b0 = bp[lane];
        s8v b1 = bp[64 + lane];
        const s8v* sp = (const s8v*)sxs;
        #pragma unroll
        for (int mt = 0; mt < 7; ++mt) {
            s8v a0 = sp[mt * 128 + lane];         // ks=0
            s8v a1 = sp[mt * 128 + 64 + lane];    // ks=1
            f4v c = {0.f, 0.f, 0.f, 0.f};
            c = __builtin_amdgcn_mfma_f32_16x16x32_bf16(a0, b0, c, 0, 0, 0);
            c = __builtin_amdgcn_mfma_f32_16x16x32_bf16(a1, b1, c, 0, 0, 0);
            union { ushort4 v; unsigned short s[4]; } cd;
            cd.v = *(const ushort4*)&CF[(((size_t)(z * 7 + mt) * 16 + nt) * 64 + lane) * 4];
            #pragma unroll
            for (int r = 0; r < 4; ++r) {
                int row = mt * 16 + g * 4 + r;
                if (row < NN) {
                    unsigned short val = f2bf(c[r] + bf2f(cd.s[r]));
                    if (z == 0) sxl[swzA(row, nt * 16 + li)] = val;
                    else        sxr[swzQ(row, (wave & 3) * 16 + li)] = val;
                }
            }
        }
        __syncthreads();

        // ---- phase 3: edge logits over this quarter's 64 cols ----
        if (evalid) {
            #pragma unroll
            for (int hb = 0; hb < 8; ++hb) {
                int h = hb * 8;
                uint4 ua = *(const uint4*)&sxl[swzA(src, q * 64 + h)];
                uint4 ub = *(const uint4*)&sxr[swzQ(dst, h)];
                const float* ap = attp + q * 64 + h;   // wave-uniform
                #define PROC(UL, UR, A0, A1) { \
                    float v0 = u2f_lo(UL) + u2f_lo(UR); \
                    float v1 = u2f_hi(UL) + u2f_hi(UR); \
                    accv = fmaf(A0, v0, accv); acca = fmaf(A0, fabsf(v0), acca); \
                    accv = fmaf(A1, v1, accv); acca = fmaf(A1, fabsf(v1), acca); }
                PROC(ua.x, ub.x, ap[0], ap[1]);
                PROC(ua.y, ub.y, ap[2], ap[3]);
                PROC(ua.z, ub.z, ap[4], ap[5]);
                PROC(ua.w, ub.w, ap[6], ap[7]);
                #undef PROC
            }
        }
        __syncthreads();
    }

    // sxs is dead now; carve lg/wv/partial from it
    float* lg      = (float*)sxs;          // 300 floats
    float* wv      = lg + 304;             // 100 floats
    float* partial = wv + 100;             // 12 floats

    // leaky_relu(v) = max(v,0) + 0.2*min(v,0) = 0.6*v + 0.4*|v|
    if (t < 300) lg[t] = evalid ? (0.6f * accv + 0.4f * acca) : -1e30f;
    __syncthreads();

    // ---- phase 4: wv[i] = sum over dst j in {i-1,i,i+1} of alpha(i->j) ----
    if (t < NN) {
        int i = t;
        float w = 0.f;
        #pragma unroll
        for (int dj = -1; dj <= 1; ++dj) {
            int j = i + dj;
            if (j < 0 || j >= NN) continue;
            float l0 = (j - 1 >= 0) ? lg[3 * (j - 1) + 2] : -1e30f;  // j-1 -> j
            float l1 = lg[3 * j + 1];                                 // j   -> j
            float l2 = (j + 1 < NN) ? lg[3 * (j + 1) + 0] : -1e30f;  // j+1 -> j
            float mx = fmaxf(fmaxf(l0, l1), l2);
            float den = expf(l0 - mx) + expf(l1 - mx) + expf(l2 - mx);
            float myl = lg[3 * i + dj + 1];
            w += expf(myl - mx) / den;
        }
        wv[i] = w;
    }
    __syncthreads();

    // ---- phase 5: pooled[col] partials per wave (rows split across waves) ----
    {
        float pa0 = 0.f, pa1 = 0.f, pa2 = 0.f, pa3 = 0.f;
        int r0 = wave * 13;
        int r1 = (r0 + 13 < NN) ? r0 + 13 : NN;
        int c0 = lane * 4;
        for (int row = r0; row < r1; ++row) {
            float wr = wv[row];
            uint2 u = *(const uint2*)&sxl[swzA(row, c0)];
            pa0 = fmaf(wr, u2f_lo(u.x), pa0);
            pa1 = fmaf(wr, u2f_hi(u.x), pa1);
            pa2 = fmaf(wr, u2f_lo(u.y), pa2);
            pa3 = fmaf(wr, u2f_hi(u.y), pa3);
        }
        float* pp = (float*)sxr;   // reuse: 8 waves x 256 cols f32 = 8 KB
        float4 pv = { pa0, pa1, pa2, pa3 };
        *(float4*)&pp[wave * HH + c0] = pv;
    }
    __syncthreads();

    // ---- phase 6: FC [256,3] + block reduce ----
    if (t < HH) {
        const float* pp = (const float*)sxr;
        float pooled = 100.f * bias[2 * HH + t];
        #pragma unroll
        for (int w = 0; w < 8; ++w) pooled += pp[w * HH + t];

        float p0 = pooled * Wfc[t * 3 + 0];
        float p1 = pooled * Wfc[t * 3 + 1];
        float p2 = pooled * Wfc[t * 3 + 2];
        #pragma unroll
        for (int off = 32; off; off >>= 1) {
            p0 += __shfl_down(p0, off, 64);
            p1 += __shfl_down(p1, off, 64);
            p2 += __shfl_down(p2, off, 64);
        }
        if (lane == 0) {
            partial[wave * 3 + 0] = p0;
            partial[wave * 3 + 1] = p1;
            partial[wave * 3 + 2] = p2;
        }
    }
    __syncthreads();
    if (t < CC) {
        out[(size_t)b * CC + t] =
            partial[0 * 3 + t] + partial[1 * 3 + t] +
            partial[2 * 3 + t] + partial[3 * 3 + t] + bfc[t];
    }
}

// ---------------------------------------------------------------------------
extern "C" void kernel_launch(void* const* d_in, const int* in_sizes, int n_in,
                              void* d_out, int out_size, void* d_ws, size_t ws_size,
                              hipStream_t stream) {
    const float* x     = (const float*)d_in[0];
    const float* W_exp = (const float*)d_in[1];
    const float* b_exp = (const float*)d_in[2];
    const float* W_l   = (const float*)d_in[3];
    const float* b_l   = (const float*)d_in[4];
    const float* W_r   = (const float*)d_in[5];
    const float* b_r   = (const float*)d_in[6];
    const float* att   = (const float*)d_in[7];
    const float* bias  = (const float*)d_in[8];
    const float* W_fc  = (const float*)d_in[9];
    const float* b_fc  = (const float*)d_in[10];
    float* out = (float*)d_out;

    // workspace layout (16B aligned)
    char* ws = (char*)d_ws;
    float* Wcomb = (float*)ws;                                             // 131072 B
    float* cadd  = (float*)(ws + 131072);                                  // 204800 B
    unsigned short* WF = (unsigned short*)(ws + 131072 + 204800);          // 65536 B
    unsigned short* CF = (unsigned short*)(ws + 131072 + 204800 + 65536);  // 114688 B

    precompute_k<<<dim3(164, 2), 256, 0, stream>>>(W_exp, b_exp, W_l, b_l, W_r, b_r,
                                                   Wcomb, cadd);
    rearrange_k<<<352, 256, 0, stream>>>(Wcomb, cadd, WF, CF);
    fused_k<<<BB, 512, 0, stream>>>(x, WF, CF, att, bias, W_fc, b_fc, out);
}

// Round 6
// 83.538 us; speedup vs baseline: 3.6360x; 1.4579x over previous
//
#include <hip/hip_runtime.h>
#include <hip/hip_bf16.h>

// Problem constants
#define BB 2048
#define NN 100
#define INF_ 64
#define HH 256
#define CC 3

typedef __attribute__((ext_vector_type(8))) short s8v;   // 8 bf16 (4 VGPRs)
typedef __attribute__((ext_vector_type(4))) float f4v;   // 4 fp32 acc

static __device__ __forceinline__ unsigned short f2bf(float f) {
    union { float f; unsigned int u; } c; c.f = f;
    unsigned int r = c.u + 0x7FFF + ((c.u >> 16) & 1);   // RNE
    return (unsigned short)(r >> 16);
}
static __device__ __forceinline__ unsigned int pk2(float lo, float hi) {
    return (unsigned int)f2bf(lo) | ((unsigned int)f2bf(hi) << 16);
}
static __device__ __forceinline__ float u2f_lo(unsigned int u) {
    union { float f; unsigned int i; } c; c.i = u << 16; return c.f;
}
static __device__ __forceinline__ float u2f_hi(unsigned int u) {
    union { float f; unsigned int i; } c; c.i = u & 0xffff0000u; return c.f;
}
// swizzled LDS element index: XOR elem bits 3..5 with row&7
static __device__ __forceinline__ int swzA(int row, int col) {   // [100][256]
    return (row * HH + col) ^ ((row & 7) << 3);
}

// ---------------------------------------------------------------------------
// Kernel P: Wcomb[z][64][256] = W_exp @ W_{l,r}[2] (f32)
//           cadd[z][100][256] = (b_exp + pe[n]) @ W_{l,r}[2] + b_{l,r}[2] (f32)
// ---------------------------------------------------------------------------
__global__ __launch_bounds__(256) void precompute_k(
    const float* __restrict__ W_exp, const float* __restrict__ b_exp,
    const float* __restrict__ W_l, const float* __restrict__ b_l,
    const float* __restrict__ W_r, const float* __restrict__ b_r,
    float* __restrict__ Wcomb, float* __restrict__ cadd)
{
    int r = blockIdx.x;           // 0..163
    int z = blockIdx.y;           // 0 = l, 1 = r
    int t = threadIdx.x;          // output col
    const float* Wg = (z ? W_r : W_l) + 2 * HH * HH;  // layer 2
    const float* bg = (z ? b_r : b_l) + 2 * HH;

    __shared__ float sa[HH];
    float a;
    if (r < INF_) {
        a = W_exp[r * HH + t];
    } else {
        int n = r - INF_;
        float div = expf((float)(t & 254) * (-0.03597789207803f));
        float ang = (float)n * div;
        a = b_exp[t] + ((t & 1) ? cosf(ang) : sinf(ang));
    }
    sa[t] = a;
    __syncthreads();

    float acc = 0.f;
    #pragma unroll 8
    for (int h = 0; h < HH; ++h)
        acc += sa[h] * Wg[h * HH + t];

    if (r < INF_) Wcomb[(z * INF_ + r) * HH + t] = acc;
    else          cadd[(z * NN + (r - INF_)) * HH + t] = acc + bg[t];
}

// ---------------------------------------------------------------------------
// Kernel R: rearrange into MFMA fragment layouts.
//  WF (bf16) [z][nt:16][ks:2][lane:64][j:8] : Wcomb[z][k][n],
//      k = ks*32 + 4*(lane>>4) + (j&3) + 16*(j>>2),  n = nt*16 + (lane&15)
//  CFf (f32) [z][mt:7][nt:16][lane:64][r:4] : cadd[z][node][feat],
//      node = mt*16 + (lane&15), feat = nt*16 + (lane>>4)*4 + r  (node>=100 -> 0)
//  (CFf matches the SWAPPED-operand D layout: D[feat][node], col=lane&15=node)
// ---------------------------------------------------------------------------
#define N_WF 32768
#define N_CF4 14336   // float4 slots

__global__ __launch_bounds__(256) void rearrange_k(
    const float* __restrict__ Wcomb, const float* __restrict__ cadd,
    unsigned short* __restrict__ WF, float* __restrict__ CFf)
{
    int i = blockIdx.x * 256 + threadIdx.x;
    if (i < N_WF) {
        int j = i & 7, lane = (i >> 3) & 63, ks = (i >> 9) & 1;
        int nt = (i >> 10) & 15, z = (i >> 14) & 1;
        int k = ks * 32 + 4 * (lane >> 4) + (j & 3) + 16 * (j >> 2);
        int n = nt * 16 + (lane & 15);
        WF[i] = f2bf(Wcomb[(z * INF_ + k) * HH + n]);
    } else if (i < N_WF + N_CF4) {
        int i2 = i - N_WF;
        int lane = i2 & 63, nt = (i2 >> 6) & 15;
        int zm = i2 >> 10;                 // 0..13
        int mt = zm % 7, z = zm / 7;
        int node = mt * 16 + (lane & 15);
        int feat = nt * 16 + (lane >> 4) * 4;
        float4 v = {0.f, 0.f, 0.f, 0.f};
        if (node < NN)
            v = *(const float4*)&cadd[(z * NN + node) * HH + feat];
        *(float4*)&CFf[(size_t)i2 * 4] = v;
    }
}

// ---------------------------------------------------------------------------
// Kernel F (fused): one block per batch, 512 threads (8 waves), 2 blocks/CU.
//  Stage x[b] -> LDS bf16 fragments. Quarter loop (64 cols): swapped-operand
//  MFMA (D[feat][node], CFf as C-init) -> software bf16 pack -> ds_write_b64
//  into row-major swizzled sxl/sxr; then balanced edge-logit accumulation
//  (2400 slots over 512 threads, register accumulators). Tail: 8-lane shfl
//  reduce -> lg, softmax->wv, pooled, FC.
// ---------------------------------------------------------------------------
__global__ __launch_bounds__(512, 4) void fused_k(
    const float* __restrict__ x,
    const unsigned short* __restrict__ WF, const float* __restrict__ CFf,
    const float* __restrict__ att, const float* __restrict__ bias,
    const float* __restrict__ Wfc, const float* __restrict__ bfc,
    float* __restrict__ out)
{
    __shared__ unsigned short sxl[NN * HH];    // 51200 B (swizzled, persistent)
    __shared__ unsigned short sxr[NN * 64];    // 12800 B (swizzled, per-quarter)
    __shared__ unsigned short sxs[896 * 8];    // 14336 B A-frags; later lg/wv/partial
    __shared__ float satt[HH];                 // 1024 B

    int b = blockIdx.x, t = threadIdx.x;
    int wave = t >> 6, lane = t & 63, g = lane >> 4, li = lane & 15;

    if (t < HH) satt[t] = att[2 * HH + t];

    // ---- stage x[b] as bf16 fragments (B-operand for swapped mfma) ----
    const float* xb = x + (size_t)b * (NN * INF_);
    for (int s = t; s < 896; s += 512) {
        int sl = s & 63, ks = (s >> 6) & 1, mt = s >> 7;
        int m = mt * 16 + (sl & 15), gg = sl >> 4;
        union { s8v v; unsigned int u[4]; } a;
        if (m < NN) {
            float4 u = *(const float4*)&xb[m * INF_ + ks * 32 + 4 * gg];
            float4 v = *(const float4*)&xb[m * INF_ + ks * 32 + 16 + 4 * gg];
            a.u[0] = pk2(u.x, u.y);
            a.u[1] = pk2(u.z, u.w);
            a.u[2] = pk2(v.x, v.y);
            a.u[3] = pk2(v.z, v.w);
        } else {
            a.u[0] = a.u[1] = a.u[2] = a.u[3] = 0u;
        }
        *(s8v*)&sxs[s * 8] = a.v;
    }

    // ---- per-thread edge slots: edges e = (t>>3)+64i, col chunk c8 = (t&7)*8 ----
    int q8 = t >> 3, c8 = (t & 7) * 8;
    int eBL[5], eBR[5];
    bool eva[5];
    float pv[5], pa[5];
    #pragma unroll
    for (int i = 0; i < 5; ++i) {
        int e = q8 + 64 * i;
        bool inr = (e < 300);
        int es = inr ? (e / 3) : 0;
        int ed = es + (e - 3 * es) - 1;          // dst
        bool v = inr && ed >= 0 && ed < NN;
        eva[i] = v;
        int dd = v ? ed : 0;
        eBL[i] = 2 * (es * HH + (c8 ^ ((es & 7) << 3)));   // byte, + q*128 per quarter
        eBR[i] = 2 * (dd * 64 + (c8 ^ ((dd & 7) << 3)));   // byte, quarter-local
        pv[i] = 0.f; pa[i] = 0.f;
    }

    int z = wave >> 2;          // waves 0-3: xl, 4-7: xr
    int ntw = wave & 3;
    __syncthreads();

    #pragma unroll
    for (int q = 0; q < 4; ++q) {
        // ---- MFMA quarter: wave owns tile (z, nt) ----
        int nt = q * 4 + ntw;
        const s8v* bp = (const s8v*)WF + (size_t)(z * 16 + nt) * 2 * 64;
        s8v w0 = bp[lane];            // ks=0 (A-operand: W^T)
        s8v w1 = bp[64 + lane];       // ks=1
        const s8v* sp = (const s8v*)sxs;
        unsigned short* dstp = z ? sxr : sxl;
        int colbase = (z ? (ntw * 16) : (nt * 16)) + g * 4;
        int rowstride = z ? 64 : HH;
        #pragma unroll
        for (int mt = 0; mt < 7; ++mt) {
            f4v c = *(const f4v*)&CFf[((size_t)((z * 7 + mt) * 16 + nt) * 64 + lane) * 4];
            s8v a0 = sp[mt * 128 + lane];
            s8v a1 = sp[mt * 128 + 64 + lane];
            c = __builtin_amdgcn_mfma_f32_16x16x32_bf16(w0, a0, c, 0, 0, 0);
            c = __builtin_amdgcn_mfma_f32_16x16x32_bf16(w1, a1, c, 0, 0, 0);
            int node = mt * 16 + li;
            if (mt < 6 || li < 4) {              // node < 100
                unsigned int lo = pk2(c[0], c[1]);
                unsigned int hi = pk2(c[2], c[3]);
                int elem = (node * rowstride + colbase) ^ ((li & 7) << 3);
                uint2 wv2 = { lo, hi };
                *(uint2*)&dstp[elem] = wv2;      // ds_write_b64, 4 features
            }
        }
        __syncthreads();

        // ---- balanced logits over this quarter's 64 cols ----
        float4 at0 = *(const float4*)&satt[q * 64 + c8];
        float4 at1 = *(const float4*)&satt[q * 64 + c8 + 4];
        #pragma unroll
        for (int i = 0; i < 5; ++i) {
            if (eva[i]) {
                uint4 ua = *(const uint4*)((const char*)sxl + (eBL[i] + q * 128));
                uint4 ub = *(const uint4*)((const char*)sxr + eBR[i]);
                float fv, fa;
                #define PROC(UL, UR, A0, A1) { \
                    float v0 = u2f_lo(UL) + u2f_lo(UR); \
                    float v1 = u2f_hi(UL) + u2f_hi(UR); \
                    fv = fmaf(A0, v0, fv); fa = fmaf(A0, fabsf(v0), fa); \
                    fv = fmaf(A1, v1, fv); fa = fmaf(A1, fabsf(v1), fa); }
                fv = 0.f; fa = 0.f;
                PROC(ua.x, ub.x, at0.x, at0.y);
                PROC(ua.y, ub.y, at0.z, at0.w);
                PROC(ua.z, ub.z, at1.x, at1.y);
                PROC(ua.w, ub.w, at1.z, at1.w);
                #undef PROC
                pv[i] += fv; pa[i] += fa;
            }
        }
        __syncthreads();
    }

    // ---- reduce slot partials across 8-lane groups -> lg ----
    float* lg      = (float*)sxs;          // 300 floats (sxs dead)
    float* wvp     = lg + 304;             // 100 floats
    float* partial = wvp + 104;            // 12 floats

    #pragma unroll
    for (int i = 0; i < 5; ++i) {
        // leaky(v) = 0.6v + 0.4|v|, factored: lg = 0.6*pv + 0.4*pa
        float s = fmaf(0.6f, pv[i], 0.4f * pa[i]);
        s += __shfl_xor(s, 1, 64);
        s += __shfl_xor(s, 2, 64);
        s += __shfl_xor(s, 4, 64);
        int e = q8 + 64 * i;
        if ((t & 7) == 0 && e < 300)
            lg[e] = eva[i] ? s : -1e30f;
    }
    __syncthreads();

    // ---- wv[i] = sum over dst j in {i-1,i,i+1} of alpha(i->j) ----
    if (t < NN) {
        int i = t;
        float w = 0.f;
        #pragma unroll
        for (int dj = -1; dj <= 1; ++dj) {
            int j = i + dj;
            if (j < 0 || j >= NN) continue;
            float l0 = (j - 1 >= 0) ? lg[3 * (j - 1) + 2] : -1e30f;  // j-1 -> j
            float l1 = lg[3 * j + 1];                                 // j   -> j
            float l2 = (j + 1 < NN) ? lg[3 * (j + 1) + 0] : -1e30f;  // j+1 -> j
            float mx = fmaxf(fmaxf(l0, l1), l2);
            float den = expf(l0 - mx) + expf(l1 - mx) + expf(l2 - mx);
            float myl = lg[3 * i + dj + 1];
            w += expf(myl - mx) / den;
        }
        wvp[i] = w;
    }
    __syncthreads();

    // ---- pooled[col] partials per wave ----
    {
        float pa0 = 0.f, pa1 = 0.f, pa2 = 0.f, pa3 = 0.f;
        int r0 = wave * 13;
        int r1 = (r0 + 13 < NN) ? r0 + 13 : NN;
        int c0 = lane * 4;
        for (int row = r0; row < r1; ++row) {
            float wr = wvp[row];
            uint2 u = *(const uint2*)&sxl[swzA(row, c0)];
            pa0 = fmaf(wr, u2f_lo(u.x), pa0);
            pa1 = fmaf(wr, u2f_hi(u.x), pa1);
            pa2 = fmaf(wr, u2f_lo(u.y), pa2);
            pa3 = fmaf(wr, u2f_hi(u.y), pa3);
        }
        float* pp = (float*)sxr;   // 8 waves x 256 cols f32 = 8 KB
        float4 pvv = { pa0, pa1, pa2, pa3 };
        *(float4*)&pp[wave * HH + c0] = pvv;
    }
    __syncthreads();

    // ---- FC [256,3] + block reduce ----
    if (t < HH) {
        const float* pp = (const float*)sxr;
        float pooled = 100.f * bias[2 * HH + t];
        #pragma unroll
        for (int w = 0; w < 8; ++w) pooled += pp[w * HH + t];

        float p0 = pooled * Wfc[t * 3 + 0];
        float p1 = pooled * Wfc[t * 3 + 1];
        float p2 = pooled * Wfc[t * 3 + 2];
        #pragma unroll
        for (int off = 32; off; off >>= 1) {
            p0 += __shfl_down(p0, off, 64);
            p1 += __shfl_down(p1, off, 64);
            p2 += __shfl_down(p2, off, 64);
        }
        if (lane == 0) {
            partial[wave * 3 + 0] = p0;
            partial[wave * 3 + 1] = p1;
            partial[wave * 3 + 2] = p2;
        }
    }
    __syncthreads();
    if (t < CC) {
        out[(size_t)b * CC + t] =
            partial[0 * 3 + t] + partial[1 * 3 + t] +
            partial[2 * 3 + t] + partial[3 * 3 + t] + bfc[t];
    }
}

// ---------------------------------------------------------------------------
extern "C" void kernel_launch(void* const* d_in, const int* in_sizes, int n_in,
                              void* d_out, int out_size, void* d_ws, size_t ws_size,
                              hipStream_t stream) {
    const float* x     = (const float*)d_in[0];
    const float* W_exp = (const float*)d_in[1];
    const float* b_exp = (const float*)d_in[2];
    const float* W_l   = (const float*)d_in[3];
    const float* b_l   = (const float*)d_in[4];
    const float* W_r   = (const float*)d_in[5];
    const float* b_r   = (const float*)d_in[6];
    const float* att   = (const float*)d_in[7];
    const float* bias  = (const float*)d_in[8];
    const float* W_fc  = (const float*)d_in[9];
    const float* b_fc  = (const float*)d_in[10];
    float* out = (float*)d_out;

    // workspace layout (16B aligned)
    char* ws = (char*)d_ws;
    float* Wcomb = (float*)ws;                                             // 131072 B
    float* cadd  = (float*)(ws + 131072);                                  // 204800 B
    unsigned short* WF = (unsigned short*)(ws + 131072 + 204800);          // 65536 B
    float* CFf = (float*)(ws + 131072 + 204800 + 65536);                   // 229376 B

    precompute_k<<<dim3(164, 2), 256, 0, stream>>>(W_exp, b_exp, W_l, b_l, W_r, b_r,
                                                   Wcomb, cadd);
    rearrange_k<<<184, 256, 0, stream>>>(Wcomb, cadd, WF, CFf);
    fused_k<<<BB, 512, 0, stream>>>(x, WF, CFf, att, bias, W_fc, b_fc, out);
}